// Round 1
// baseline (161.338 us; speedup 1.0000x reference)
//
#include <hip/hip_runtime.h>
#include <math.h>

#define NTHREADS 256

// 16 node weight pointers + per-node per-physical-slice element counts.
struct PW {
    const float* w[16];
    int perp[16];
};

// ---------------------------------------------------------------------------
// Gram precompute: for each node n, G00=<w0,w0>, G01=<w0,w1>, G11=<w1,w1>.
// One block per node, written to d_ws[n*3 .. n*3+2]. Re-run every launch
// (d_ws is re-poisoned by the harness).
// ---------------------------------------------------------------------------
__global__ __launch_bounds__(NTHREADS) void gram16(PW pw, float* __restrict__ g) {
    const int n = blockIdx.x;
    const float* __restrict__ W = pw.w[n];
    const int m = pw.perp[n];
    float s00 = 0.f, s01 = 0.f, s11 = 0.f;
    for (int e = threadIdx.x; e < m; e += NTHREADS) {
        float a = W[e], b = W[m + e];
        s00 += a * a; s01 += a * b; s11 += b * b;
    }
    for (int off = 32; off > 0; off >>= 1) {
        s00 += __shfl_down(s00, off, 64);
        s01 += __shfl_down(s01, off, 64);
        s11 += __shfl_down(s11, off, 64);
    }
    __shared__ float red[4][3];
    const int lane = threadIdx.x & 63, wv = threadIdx.x >> 6;
    if (lane == 0) { red[wv][0] = s00; red[wv][1] = s01; red[wv][2] = s11; }
    __syncthreads();
    if (threadIdx.x == 0) {
        float t0 = 0.f, t1 = 0.f, t2 = 0.f;
        for (int i = 0; i < 4; i++) { t0 += red[i][0]; t1 += red[i][1]; t2 += red[i][2]; }
        g[n * 3 + 0] = t0; g[n * 3 + 1] = t1; g[n * 3 + 2] = t2;
    }
}

// ---------------------------------------------------------------------------
// Generic small contraction: out[x1,x2,y1,y2] = sum_{u,l} A[...]*B[...]
// All sizes/strides compile-time -> fully unrolled inner loops, y2 runs give
// the compiler contiguous LDS reads (BY2==1 on every big step).
// ---------------------------------------------------------------------------
template<int X1, int X2, int Y1, int Y2, int U, int L,
         int AX1, int AX2, int AU, int AL,
         int BU, int BLs, int BY1, int BY2,
         int OX1, int OX2, int OY1, int OY2>
__device__ __forceinline__ void contract(const float* __restrict__ A,
                                         const float* __restrict__ Bm,
                                         float* __restrict__ O, int tid) {
    constexpr int ROWS = X1 * X2 * Y1;   // each "row" = Y2 outputs
    for (int r = tid; r < ROWS; r += NTHREADS) {
        const int x1 = r / (X2 * Y1);
        const int rm = r - x1 * (X2 * Y1);
        const int x2 = rm / Y1;
        const int y1 = rm - x2 * Y1;
        const float* __restrict__ Ab = A + x1 * AX1 + x2 * AX2;
        const float* __restrict__ Bb = Bm + y1 * BY1;
        float acc[Y2];
#pragma unroll
        for (int t = 0; t < Y2; t++) acc[t] = 0.f;
#pragma unroll
        for (int u = 0; u < U; u++) {
#pragma unroll
            for (int l = 0; l < L; l++) {
                const float a = Ab[u * AU + l * AL];
                const float* __restrict__ Bp = Bb + u * BU + l * BLs;
#pragma unroll
                for (int t = 0; t < Y2; t++) acc[t] += a * Bp[t * BY2];
            }
        }
        float* __restrict__ Ob = O + x1 * OX1 + x2 * OX2 + y1 * OY1;
#pragma unroll
        for (int t = 0; t < Y2; t++) Ob[t * OY2] = acc[t];
    }
}

// t = alpha*w0 + beta*w1 (physical-leg contraction of one node) into LDS.
__device__ __forceinline__ void tmat(float* __restrict__ dst, const float* __restrict__ W,
                                     int m, float al, float be, int tid) {
    for (int e = tid; e < m; e += NTHREADS) dst[e] = al * W[e] + be * W[m + e];
}

// ---------------------------------------------------------------------------
// Main kernel: one block = one sample. Quadrant contraction:
//   TL(2x2 top-left), TR(2x2 top-right), BL(2x2 bottom-left),
//   R = {(2,3),(3,2),(3,3)}, TOP = TL x TR, M1 = TOP x BL, E = M1 x R,
//   out = E x t22, then L2-normalize.
// Max intermediate 1296 floats; all node normalizations cancel in the final
// normalize, so alpha/beta fold the norms via the Gram table.
// ---------------------------------------------------------------------------
__global__ __launch_bounds__(NTHREADS) void peps_main(const float* __restrict__ x, PW pw,
                                                      const float* __restrict__ gram,
                                                      float* __restrict__ out) {
    __shared__ float B1[1296], B2[1296], B3[1296], B4[1296], B5[1296];
    __shared__ float tX[1296], tY[1296];
    __shared__ float cfa[16], cfb[16];
    __shared__ float red[4][10];

    const int tid = threadIdx.x;
    const int s = blockIdx.x;

    // per-node normalized coefficients: t_ij = (a*w0 + b*w1)/||.||
    if (tid < 16) {
        const float a = x[s * 32 + tid * 2 + 0];
        const float b = x[s * 32 + tid * 2 + 1];
        const float g0 = gram[tid * 3 + 0], g1 = gram[tid * 3 + 1], g2 = gram[tid * 3 + 2];
        const float inv = 1.f / sqrtf(a * a * g0 + 2.f * a * b * g1 + b * b * g2);
        cfa[tid] = a * inv; cfb[tid] = b * inv;
    }
    __syncthreads();

#define SYNC __syncthreads()

    // ---- TL quadrant: nodes (0,0),(0,1),(1,0),(1,1) ----
    // S1: TL1[v00,v01,h01] = sum_{h00} t00 * t01
    tmat(tX, pw.w[0], 36, cfa[0], cfb[0], tid);
    tmat(tY, pw.w[1], 216, cfa[1], cfb[1], tid);
    SYNC;
    contract<1, 6, 6, 6, 6, 1,   0, 6, 1, 0,   36, 0, 6, 1,   0, 36, 6, 1>(tX, tY, B1, tid);
    SYNC;
    // S2: TL2[v01,h01,v10,h10] = sum_{v00} TL1 * t10
    tmat(tX, pw.w[4], 216, cfa[4], cfb[4], tid);
    SYNC;
    contract<1, 36, 6, 6, 6, 1,   0, 1, 36, 0,   36, 0, 6, 1,   0, 36, 6, 1>(B1, tX, B2, tid);
    SYNC;
    // S3: TL[h01,v10,v11,h11] = sum_{v01,h10} TL2 * t11
    tmat(tY, pw.w[5], 1296, cfa[5], cfb[5], tid);
    SYNC;
    contract<6, 6, 6, 6, 6, 6,   36, 6, 216, 1,   216, 36, 6, 1,   216, 36, 6, 1>(B2, tY, B3, tid);
    SYNC;

    // ---- TR quadrant: nodes (0,2),(0,3),(1,2),(1,3) ----
    // S4: TR1[h01,v02,v03] = sum_{h02} t02 * t03
    tmat(tX, pw.w[2], 216, cfa[2], cfb[2], tid);
    tmat(tY, pw.w[3], 36, cfa[3], cfb[3], tid);
    SYNC;
    contract<1, 36, 1, 6, 6, 1,   0, 6, 1, 0,   6, 0, 0, 1,   0, 6, 0, 1>(tX, tY, B1, tid);
    SYNC;
    // S5: TR2[h01,v02,h12,v13] = sum_{v03} TR1 * t13
    tmat(tX, pw.w[7], 216, cfa[7], cfb[7], tid);
    SYNC;
    contract<1, 36, 6, 6, 6, 1,   0, 6, 1, 0,   36, 0, 6, 1,   0, 36, 6, 1>(B1, tX, B2, tid);
    SYNC;
    // S6: TR'[h11,v12,h01,v13] = sum_{v02,h12} t12 * TR2   (A = t12!)
    tmat(tY, pw.w[6], 1296, cfa[6], cfb[6], tid);
    SYNC;
    contract<6, 6, 6, 6, 6, 6,   36, 6, 216, 1,   36, 6, 216, 1,   216, 36, 6, 1>(tY, B2, B4, tid);
    SYNC;
    // S7: TOP[v10,v11,v12,v13] = sum_{h01,h11} TL * TR'
    contract<6, 6, 6, 6, 6, 6,   36, 6, 216, 1,   6, 216, 36, 1,   216, 36, 6, 1>(B3, B4, B1, tid);
    SYNC;

    // ---- BL quadrant: nodes (2,0),(2,1),(3,0),(3,1) ----
    // S8: BL1[h30,v10,h20] = sum_{v20} t30 * t20
    tmat(tX, pw.w[12], 36, cfa[12], cfb[12], tid);
    tmat(tY, pw.w[8], 216, cfa[8], cfb[8], tid);
    SYNC;
    contract<1, 6, 6, 6, 6, 1,   0, 1, 6, 0,   6, 0, 36, 1,   0, 36, 6, 1>(tX, tY, B2, tid);
    SYNC;
    // S9: BL2[v10,h20,v21,h31] = sum_{h30} BL1 * t31
    tmat(tX, pw.w[13], 216, cfa[13], cfb[13], tid);
    SYNC;
    contract<1, 36, 6, 6, 6, 1,   0, 1, 36, 0,   6, 0, 36, 1,   0, 36, 6, 1>(B2, tX, B5, tid);
    SYNC;
    // S10: BL[v10,h31,v11,h21] = sum_{h20,v21} BL2 * t21
    tmat(tY, pw.w[9], 1296, cfa[9], cfb[9], tid);
    SYNC;
    contract<6, 6, 6, 6, 6, 6,   216, 1, 36, 6,   36, 6, 216, 1,   216, 36, 6, 1>(B5, tY, B3, tid);
    SYNC;

    // ---- R corner: nodes (2,3),(3,2),(3,3) ----
    // S11: R1[v13,h22,h32] = sum_{v23} t23 * t33
    tmat(tX, pw.w[11], 216, cfa[11], cfb[11], tid);
    tmat(tY, pw.w[15], 36, cfa[15], cfb[15], tid);
    SYNC;
    contract<6, 6, 1, 6, 6, 1,   36, 6, 1, 0,   6, 0, 0, 1,   36, 6, 0, 1>(tX, tY, B2, tid);
    SYNC;
    // S12: R'[v13,h31,v22,h22] = sum_{h32} R1 * t32   (custom out strides)
    tmat(tX, pw.w[14], 216, cfa[14], cfb[14], tid);
    SYNC;
    contract<6, 6, 6, 6, 6, 1,   36, 6, 1, 0,   1, 0, 36, 6,   216, 1, 6, 36>(B2, tX, B4, tid);
    SYNC;

    // ---- combine ----
    // S13: M1[v12,v13,h31,h21] = sum_{v10,v11} TOP * BL
    contract<6, 6, 6, 6, 6, 6,   6, 1, 216, 36,   216, 6, 36, 1,   216, 36, 6, 1>(B1, B3, B5, tid);
    SYNC;
    // S14: E[v12,h21,v22,h22] = sum_{v13,h31} M1 * R'   (env of center node)
    contract<6, 6, 6, 6, 6, 6,   216, 1, 36, 6,   216, 36, 6, 1,   216, 36, 6, 1>(B5, B4, B2, tid);
    SYNC;

    // ---- S15: out[o] = sum_e E[e] * (a*w22_0[e,o] + b*w22_1[e,o]); normalize ----
    {
        const float al = cfa[10], be = cfb[10];
        const float* __restrict__ w0 = pw.w[10];
        const float* __restrict__ w1 = w0 + 12960;
        float part[10];
#pragma unroll
        for (int o = 0; o < 10; o++) part[o] = 0.f;
        for (int e = tid; e < 1296; e += NTHREADS) {
            const float Ev = B2[e];
            const float* __restrict__ p0 = w0 + e * 10;
            const float* __restrict__ p1 = w1 + e * 10;
#pragma unroll
            for (int o = 0; o < 10; o++) part[o] += Ev * (al * p0[o] + be * p1[o]);
        }
#pragma unroll
        for (int o = 0; o < 10; o++)
            for (int off = 32; off > 0; off >>= 1)
                part[o] += __shfl_down(part[o], off, 64);
        const int lane = tid & 63, wv = tid >> 6;
        if (lane == 0) {
#pragma unroll
            for (int o = 0; o < 10; o++) red[wv][o] = part[o];
        }
        __syncthreads();
        if (tid == 0) {
            float r[10];
            float ss = 0.f;
#pragma unroll
            for (int o = 0; o < 10; o++) {
                r[o] = red[0][o] + red[1][o] + red[2][o] + red[3][o];
                ss += r[o] * r[o];
            }
            const float inv = 1.f / sqrtf(ss);
#pragma unroll
            for (int o = 0; o < 10; o++) out[s * 10 + o] = r[o] * inv;
        }
    }
#undef SYNC
}

extern "C" void kernel_launch(void* const* d_in, const int* in_sizes, int n_in,
                              void* d_out, int out_size, void* d_ws, size_t ws_size,
                              hipStream_t stream) {
    PW pw;
    for (int k = 0; k < 16; k++) {
        pw.w[k] = (const float*)d_in[1 + k];
        pw.perp[k] = in_sizes[1 + k] / 2;   // elements per physical slice
    }
    float* gram = (float*)d_ws;             // 16*3 floats
    gram16<<<16, NTHREADS, 0, stream>>>(pw, gram);

    const float* x = (const float*)d_in[0];
    const int B = out_size / 10;            // 2048 samples
    peps_main<<<B, NTHREADS, 0, stream>>>(x, pw, gram, (float*)d_out);
}

// Round 2
// 157.823 us; speedup vs baseline: 1.0223x; 1.0223x over previous
//
#include <hip/hip_runtime.h>
#include <math.h>

#define NTHREADS 256

// 16 node weight pointers.
struct PW {
    const float* w[16];
    int perp[16];
};

// ---------------------------------------------------------------------------
// Gram precompute: per node n, G00=<w0,w0>, G01=<w0,w1>, G11=<w1,w1> -> d_ws.
// ---------------------------------------------------------------------------
__global__ __launch_bounds__(NTHREADS) void gram16(PW pw, float* __restrict__ g) {
    const int n = blockIdx.x;
    const float* __restrict__ W = pw.w[n];
    const int m = pw.perp[n];
    float s00 = 0.f, s01 = 0.f, s11 = 0.f;
    for (int e = threadIdx.x; e < m; e += NTHREADS) {
        float a = W[e], b = W[m + e];
        s00 += a * a; s01 += a * b; s11 += b * b;
    }
    for (int off = 32; off > 0; off >>= 1) {
        s00 += __shfl_down(s00, off, 64);
        s01 += __shfl_down(s01, off, 64);
        s11 += __shfl_down(s11, off, 64);
    }
    __shared__ float red[4][3];
    const int lane = threadIdx.x & 63, wv = threadIdx.x >> 6;
    if (lane == 0) { red[wv][0] = s00; red[wv][1] = s01; red[wv][2] = s11; }
    __syncthreads();
    if (threadIdx.x == 0) {
        float t0 = 0.f, t1 = 0.f, t2 = 0.f;
        for (int i = 0; i < 4; i++) { t0 += red[i][0]; t1 += red[i][1]; t2 += red[i][2]; }
        g[n * 3 + 0] = t0; g[n * 3 + 1] = t1; g[n * 3 + 2] = t2;
    }
}

// ---------------------------------------------------------------------------
// LDS arena layout per sample (floats). 2 samples per block.
// ---------------------------------------------------------------------------
constexpr int C1 = 0, C2 = 1296, C3 = 2592, PB = 3888;
constexpr int T00 = 4104, T01 = 4140, T10 = 4356, T11 = 4572;
constexpr int T02 = 5868, T03 = 6084, T13 = 6120, T12 = 6336;
constexpr int T30 = 7632, T20 = 7668, T31 = 7884, T21 = 8100;
constexpr int T23 = 9396, T33 = 9612, T32 = 9648;
constexpr int ARENA = 9864;

// Stage one node's t = al*w0 + be*w1 into both samples' arenas.
template<int M, int DST>
__device__ __forceinline__ void tmat2(float* __restrict__ lds, const float* __restrict__ W,
                                      float a0, float b0, float a1, float b1, int tid) {
    for (int e = tid; e < 2 * M; e += NTHREADS) {
        const int s = (e >= M) ? 1 : 0;
        const int idx = e - s * M;
        const float al = s ? a1 : a0;
        const float be = s ? b1 : b0;
        lds[s * ARENA + DST + idx] = al * W[idx] + be * W[M + idx];
    }
}

// ---------------------------------------------------------------------------
// Contraction step over BOTH samples with TX-wide register tiling on x2:
//   out[x1,x2,y1,y2] = sum_{u,l} A[..]*B[..], thread tile = TX x Y2 outputs.
// ---------------------------------------------------------------------------
template<int X1, int X2, int Y1, int Y2, int U, int L, int TX,
         int AX1, int AX2, int AU, int AL,
         int BU, int BLS, int BY1, int BY2,
         int OX1, int OX2, int OY1, int OY2,
         int AOFF, int BOFF, int OOFF>
__device__ __forceinline__ void step2(float* __restrict__ lds, int tid) {
    constexpr int XB = X2 / TX;
    constexpr int TILES = X1 * XB * Y1;
    constexpr int TOT = 2 * TILES;
    for (int t = tid; t < TOT; t += NTHREADS) {
        const int sl = t / TILES;
        const int r = t - sl * TILES;
        const int x1 = r / (XB * Y1);
        const int rm = r - x1 * (XB * Y1);
        const int xb = rm / Y1;
        const int y1 = rm - xb * Y1;
        const float* __restrict__ Ab = lds + sl * ARENA + AOFF + x1 * AX1 + xb * TX * AX2;
        const float* __restrict__ Bb = lds + sl * ARENA + BOFF + y1 * BY1;
        float acc[TX][Y2];
#pragma unroll
        for (int i = 0; i < TX; i++)
#pragma unroll
            for (int t2 = 0; t2 < Y2; t2++) acc[i][t2] = 0.f;
#pragma unroll
        for (int u = 0; u < U; u++) {
#pragma unroll
            for (int l = 0; l < L; l++) {
                float a[TX];
#pragma unroll
                for (int i = 0; i < TX; i++) a[i] = Ab[i * AX2 + u * AU + l * AL];
                const float* __restrict__ Bp = Bb + u * BU + l * BLS;
#pragma unroll
                for (int t2 = 0; t2 < Y2; t2++) {
                    const float bv = Bp[t2 * BY2];
#pragma unroll
                    for (int i = 0; i < TX; i++) acc[i][t2] += a[i] * bv;
                }
            }
        }
        float* __restrict__ Ob = lds + sl * ARENA + OOFF + x1 * OX1 + xb * TX * OX2 + y1 * OY1;
#pragma unroll
        for (int i = 0; i < TX; i++)
#pragma unroll
            for (int t2 = 0; t2 < Y2; t2++) Ob[i * OX2 + t2 * OY2] = acc[i][t2];
    }
}

// ---------------------------------------------------------------------------
// Main: one block = 2 samples. Quadrant contraction, all t-mats staged once.
// ---------------------------------------------------------------------------
__global__ __launch_bounds__(NTHREADS) void peps_main(const float* __restrict__ x, PW pw,
                                                      const float* __restrict__ gram,
                                                      float* __restrict__ out) {
    __shared__ float lds[2 * ARENA];
    __shared__ float cfa[2][16], cfb[2][16];
    __shared__ float red[4][2][10];

    const int tid = threadIdx.x;
    const int s0 = blockIdx.x * 2;

    // per-node normalized coefficients for both samples
    if (tid < 32) {
        const int sl = tid >> 4, n = tid & 15;
        const float a = x[(s0 + sl) * 32 + n * 2 + 0];
        const float b = x[(s0 + sl) * 32 + n * 2 + 1];
        const float g0 = gram[n * 3 + 0], g1 = gram[n * 3 + 1], g2 = gram[n * 3 + 2];
        const float inv = 1.f / sqrtf(a * a * g0 + 2.f * a * b * g1 + b * b * g2);
        cfa[sl][n] = a * inv; cfb[sl][n] = b * inv;
    }
    __syncthreads();

    // ---- stage all 15 non-center t-matrices (single barrier after) ----
#define TM(M, DST, WI) tmat2<M, DST>(lds, pw.w[WI], cfa[0][WI], cfb[0][WI], cfa[1][WI], cfb[1][WI], tid)
    TM(36, T00, 0);  TM(216, T01, 1);  TM(216, T10, 4);  TM(1296, T11, 5);
    TM(216, T02, 2); TM(36, T03, 3);   TM(216, T13, 7);  TM(1296, T12, 6);
    TM(36, T30, 12); TM(216, T20, 8);  TM(216, T31, 13); TM(1296, T21, 9);
    TM(216, T23, 11); TM(36, T33, 15); TM(216, T32, 14);
#undef TM
    __syncthreads();

#define SYNC __syncthreads()
    // S1: TL1[v00,v01,h01] = sum_{h00} t00*t01                -> PB
    step2<1, 6, 6, 6, 6, 1, 2,  0, 6, 1, 0,   36, 0, 6, 1,   0, 36, 6, 1,  T00, T01, PB>(lds, tid); SYNC;
    // S2: TL2[v01,h01,v10,h10] = sum_{v00} TL1*t10            -> C1
    step2<1, 36, 6, 6, 6, 1, 2,  0, 1, 36, 0,  36, 0, 6, 1,   0, 36, 6, 1,  PB, T10, C1>(lds, tid); SYNC;
    // S3: TL[h01,v10,v11,h11] = sum_{v01,h10} TL2*t11         -> C2
    step2<6, 6, 6, 6, 6, 6, 2,  36, 6, 216, 1, 216, 36, 6, 1, 216, 36, 6, 1, C1, T11, C2>(lds, tid); SYNC;
    // S4: TR1[h01,v02,v03] = sum_{h02} t02*t03                -> PB
    step2<1, 36, 1, 6, 6, 1, 2,  0, 6, 1, 0,   6, 0, 0, 1,    0, 6, 0, 1,   T02, T03, PB>(lds, tid); SYNC;
    // S5: TR2[h01,v02,h12,v13] = sum_{v03} TR1*t13            -> C1
    step2<1, 36, 6, 6, 6, 1, 2,  0, 6, 1, 0,   36, 0, 6, 1,   0, 36, 6, 1,  PB, T13, C1>(lds, tid); SYNC;
    // S6: TR'[h11,v12,h01,v13] = sum_{v02,h12} t12*TR2        -> C3
    step2<6, 6, 6, 6, 6, 6, 2,  36, 6, 216, 1, 36, 6, 216, 1, 216, 36, 6, 1, T12, C1, C3>(lds, tid); SYNC;
    // S7: TOP[v10,v11,v12,v13] = sum_{h01,h11} TL*TR'         -> C1
    step2<6, 6, 6, 6, 6, 6, 2,  36, 6, 216, 1, 6, 216, 36, 1, 216, 36, 6, 1, C2, C3, C1>(lds, tid); SYNC;
    // S8: BL1[h30,v10,h20] = sum_{v20} t30*t20                -> PB
    step2<1, 6, 6, 6, 6, 1, 2,  0, 1, 6, 0,    6, 0, 36, 1,   0, 36, 6, 1,  T30, T20, PB>(lds, tid); SYNC;
    // S9: BL2[v10,h20,v21,h31] = sum_{h30} BL1*t31            -> C2
    step2<1, 36, 6, 6, 6, 1, 2,  0, 1, 36, 0,  6, 0, 36, 1,   0, 36, 6, 1,  PB, T31, C2>(lds, tid); SYNC;
    // S10: BL[v10,h31,v11,h21] = sum_{h20,v21} BL2*t21        -> C3
    step2<6, 6, 6, 6, 6, 6, 2,  216, 1, 36, 6, 36, 6, 216, 1, 216, 36, 6, 1, C2, T21, C3>(lds, tid); SYNC;
    // S11: M1[v12,v13,h31,h21] = sum_{v10,v11} TOP*BL         -> C2
    step2<6, 6, 6, 6, 6, 6, 2,  6, 1, 216, 36, 216, 6, 36, 1, 216, 36, 6, 1, C1, C3, C2>(lds, tid); SYNC;
    // S12: R1[v13,h22,h32] = sum_{v23} t23*t33                -> PB
    step2<6, 6, 1, 6, 6, 1, 2,  36, 6, 1, 0,   6, 0, 0, 1,    36, 6, 0, 1,  T23, T33, PB>(lds, tid); SYNC;
    // S13: R'[v13,h31,v22,h22] = sum_{h32} R1*t32             -> C1
    step2<6, 6, 6, 6, 6, 1, 2,  36, 6, 1, 0,   1, 0, 36, 6,   216, 1, 6, 36, PB, T32, C1>(lds, tid); SYNC;
    // S14: E[v12,h21,v22,h22] = sum_{v13,h31} M1*R'           -> C3
    step2<6, 6, 6, 6, 6, 6, 2,  216, 1, 36, 6, 216, 36, 6, 1, 216, 36, 6, 1, C2, C1, C3>(lds, tid); SYNC;

    // ---- epilogue: out[o] = sum_e E[e]*(a*w22_0[e,o]+b*w22_1[e,o]); normalize ----
    {
        const float a0 = cfa[0][10], b0 = cfb[0][10];
        const float a1 = cfa[1][10], b1 = cfb[1][10];
        const float* __restrict__ w0 = pw.w[10];
        const float* __restrict__ w1 = w0 + 12960;
        float p0[10], p1[10];
#pragma unroll
        for (int o = 0; o < 10; o++) { p0[o] = 0.f; p1[o] = 0.f; }
        for (int e = tid; e < 1296; e += NTHREADS) {
            const float E0 = lds[C3 + e];
            const float E1 = lds[ARENA + C3 + e];
            const float* __restrict__ q0 = w0 + e * 10;
            const float* __restrict__ q1 = w1 + e * 10;
#pragma unroll
            for (int o = 0; o < 10; o++) {
                const float v0 = q0[o], v1 = q1[o];
                p0[o] += E0 * (a0 * v0 + b0 * v1);
                p1[o] += E1 * (a1 * v0 + b1 * v1);
            }
        }
#pragma unroll
        for (int o = 0; o < 10; o++)
            for (int off = 32; off > 0; off >>= 1) {
                p0[o] += __shfl_down(p0[o], off, 64);
                p1[o] += __shfl_down(p1[o], off, 64);
            }
        const int lane = tid & 63, wv = tid >> 6;
        if (lane == 0) {
#pragma unroll
            for (int o = 0; o < 10; o++) { red[wv][0][o] = p0[o]; red[wv][1][o] = p1[o]; }
        }
        __syncthreads();
        if (tid < 2) {
            float r[10];
            float ss = 0.f;
#pragma unroll
            for (int o = 0; o < 10; o++) {
                r[o] = red[0][tid][o] + red[1][tid][o] + red[2][tid][o] + red[3][tid][o];
                ss += r[o] * r[o];
            }
            const float inv = 1.f / sqrtf(ss);
#pragma unroll
            for (int o = 0; o < 10; o++) out[(s0 + tid) * 10 + o] = r[o] * inv;
        }
    }
#undef SYNC
}

extern "C" void kernel_launch(void* const* d_in, const int* in_sizes, int n_in,
                              void* d_out, int out_size, void* d_ws, size_t ws_size,
                              hipStream_t stream) {
    PW pw;
    for (int k = 0; k < 16; k++) {
        pw.w[k] = (const float*)d_in[1 + k];
        pw.perp[k] = in_sizes[1 + k] / 2;
    }
    float* gram = (float*)d_ws;             // 16*3 floats
    gram16<<<16, NTHREADS, 0, stream>>>(pw, gram);

    const float* x = (const float*)d_in[0];
    const int B = out_size / 10;            // 2048 samples
    peps_main<<<B / 2, NTHREADS, 0, stream>>>(x, pw, gram, (float*)d_out);
}